// Round 10
// baseline (209.138 us; speedup 1.0000x reference)
//
#include <hip/hip_runtime.h>

#define B_  4
#define N_  4096
#define C_  256
#define D_  128
#define M_  4095
#define BN_ (B_ * N_)
#define KSPLIT 6

typedef _Float16 half_t;
typedef __attribute__((ext_vector_type(8))) _Float16 half8;
typedef __attribute__((ext_vector_type(4))) _Float16 half4;
typedef __attribute__((ext_vector_type(4))) float f32x4;

#define MFMA16x16x32(A, B, C) __builtin_amdgcn_mfma_f32_16x16x32_f16(A, B, C, 0, 0, 0)
#define LOG2E 1.44269504088896f

// ---- prep: weights into B-fragment layouts (runs once, tiny) ----
__global__ __launch_bounds__(256) void prep_kernel(
    const float* __restrict__ Wt, const float* __restrict__ Wp,
    const float* __restrict__ Wg, const float* __restrict__ Wf,
    half_t* __restrict__ WT_hi, half_t* __restrict__ WT_lo,
    half_t* __restrict__ WfT)
{
    const int idx = blockIdx.x * 256 + threadIdx.x;   // 0..32767
    const int wsel = blockIdx.y;
    if (wsel < 3) {
        const float* __restrict__ W = (wsel == 0) ? Wt : (wsel == 1) ? Wp : Wg;
        const int d = idx >> 8, c = idx & 255;
        const float v = W[(size_t)c * D_ + d];
        const half_t h = (half_t)v;
        WT_hi[(size_t)wsel * 32768 + idx] = h;
        WT_lo[(size_t)wsel * 32768 + idx] = (half_t)(v - (float)h);
    } else {
        const int c = idx >> 7, d = idx & 127;
        WfT[idx] = (half_t)Wf[(size_t)d * C_ + c];
    }
}

// ---- proj (MFMA, 3-term split ~= fp32) + FUSED maxpool/transpose ----
// which: 0 = theta*log2e -> fp16 [n][d]; 1 = phi -> pphi[m][d] f16;
// 2 = g -> pgT[d][m] f16. grid (BN_/128, 3), block 256. LDS = 40,960 B.
__global__ __launch_bounds__(256) void proj_kernel(
    const float* __restrict__ x, const half_t* __restrict__ WT_hi,
    const half_t* __restrict__ WT_lo, half_t* __restrict__ theta,
    half_t* __restrict__ pphi, half_t* __restrict__ pgT)
{
    const int tid = threadIdx.x;
    const int lane = tid & 63;
    const int w = tid >> 6;
    const int lm = lane & 15;
    const int lq = lane >> 4;
    const int r0 = blockIdx.x * 128;
    const int which = blockIdx.y;
    const half_t* __restrict__ Wh_g = WT_hi + (size_t)which * 32768;
    const half_t* __restrict__ Wl_g = WT_lo + (size_t)which * 32768;

    __shared__ __align__(16) unsigned char lds_raw[40960];
    half_t (*Xh)[40]  = (half_t (*)[40])(lds_raw);
    half_t (*Xl)[40]  = (half_t (*)[40])(lds_raw + 10240);
    half_t (*Whl)[40] = (half_t (*)[40])(lds_raw + 20480);
    half_t (*Wll)[40] = (half_t (*)[40])(lds_raw + 30720);

    f32x4 acc[2][8];
#pragma unroll
    for (int rb = 0; rb < 2; ++rb)
#pragma unroll
        for (int nb = 0; nb < 8; ++nb)
#pragma unroll
            for (int r = 0; r < 4; ++r) acc[rb][nb][r] = 0.f;

    const int sr = tid >> 1;
    const int cL = (tid & 1) * 16;

    for (int kc = 0; kc < 8; ++kc) {
        __syncthreads();
        {
            const float* xs = x + (size_t)(r0 + sr) * C_ + kc * 32 + cL;
            float vv[16];
            float4 v0 = *(const float4*)&xs[0], v1 = *(const float4*)&xs[4];
            float4 v2 = *(const float4*)&xs[8], v3 = *(const float4*)&xs[12];
            vv[0]=v0.x; vv[1]=v0.y; vv[2]=v0.z; vv[3]=v0.w;
            vv[4]=v1.x; vv[5]=v1.y; vv[6]=v1.z; vv[7]=v1.w;
            vv[8]=v2.x; vv[9]=v2.y; vv[10]=v2.z; vv[11]=v2.w;
            vv[12]=v3.x; vv[13]=v3.y; vv[14]=v3.z; vv[15]=v3.w;
            half8 hi[2], lo[2];
#pragma unroll
            for (int j = 0; j < 16; ++j) {
                half_t h = (half_t)vv[j];
                hi[j >> 3][j & 7] = h;
                lo[j >> 3][j & 7] = (half_t)(vv[j] - (float)h);
            }
            *(half8*)&Xh[sr][cL] = hi[0]; *(half8*)&Xh[sr][cL + 8] = hi[1];
            *(half8*)&Xl[sr][cL] = lo[0]; *(half8*)&Xl[sr][cL + 8] = lo[1];
            const half_t* wh = Wh_g + (size_t)sr * 256 + kc * 32 + cL;
            const half_t* wl = Wl_g + (size_t)sr * 256 + kc * 32 + cL;
            *(half8*)&Whl[sr][cL] = *(const half8*)&wh[0];
            *(half8*)&Whl[sr][cL + 8] = *(const half8*)&wh[8];
            *(half8*)&Wll[sr][cL] = *(const half8*)&wl[0];
            *(half8*)&Wll[sr][cL + 8] = *(const half8*)&wl[8];
        }
        __syncthreads();

        half8 ah[2], al[2];
#pragma unroll
        for (int rb = 0; rb < 2; ++rb) {
            ah[rb] = *(const half8*)&Xh[w * 32 + rb * 16 + lm][lq * 8];
            al[rb] = *(const half8*)&Xl[w * 32 + rb * 16 + lm][lq * 8];
        }
#pragma unroll
        for (int nb = 0; nb < 8; ++nb) {
            half8 bh = *(const half8*)&Whl[nb * 16 + lm][lq * 8];
            half8 bl = *(const half8*)&Wll[nb * 16 + lm][lq * 8];
#pragma unroll
            for (int rb = 0; rb < 2; ++rb) {
                acc[rb][nb] = MFMA16x16x32(ah[rb], bh, acc[rb][nb]);
                acc[rb][nb] = MFMA16x16x32(al[rb], bh, acc[rb][nb]);
                acc[rb][nb] = MFMA16x16x32(ah[rb], bl, acc[rb][nb]);
            }
        }
    }

    if (which == 0) {   // theta: scale by log2e, store fp16 (QK runs in base-2)
#pragma unroll
        for (int rb = 0; rb < 2; ++rb)
#pragma unroll
            for (int nb = 0; nb < 8; ++nb)
#pragma unroll
                for (int r = 0; r < 4; ++r)
                    theta[(size_t)(r0 + w * 32 + rb * 16 + lq * 4 + r) * D_ +
                          nb * 16 + lm] = (half_t)(acc[rb][nb][r] * LOG2E);
        return;
    }

    // ---- fused pool path: acc -> LsT[d][m] fp16, halo row, pool, store ----
    __syncthreads();   // staging arrays dead
    half_t (*LsT)[136] = (half_t (*)[136])(lds_raw);   // 128 x 136 = 34,816 B
#pragma unroll
    for (int rb = 0; rb < 2; ++rb)
#pragma unroll
        for (int nb = 0; nb < 8; ++nb) {
            const int d = nb * 16 + lm;
            const int m = w * 32 + rb * 16 + lq * 4;
            half4 pk;
#pragma unroll
            for (int r = 0; r < 4; ++r) pk[r] = (half_t)acc[rb][nb][r];
            *(half4*)&LsT[d][m] = pk;
        }
    // halo: projected row r0+128 (or r0+127 at batch boundary) -> LsT[d][128]
    if (tid < 128) {
        int rh = r0 + 128;
        if ((rh & (N_ - 1)) == 0) rh = r0 + 127;
        const float* xr = x + (size_t)rh * C_;
        const half_t* wh = Wh_g + (size_t)tid * 256;
        const half_t* wl = Wl_g + (size_t)tid * 256;
        float s = 0.f;
#pragma unroll
        for (int c8 = 0; c8 < 32; ++c8) {
            half8 h = *(const half8*)&wh[c8 * 8];
            half8 l = *(const half8*)&wl[c8 * 8];
            float4 xa = *(const float4*)&xr[c8 * 8];
            float4 xb = *(const float4*)&xr[c8 * 8 + 4];
            s += xa.x * ((float)h[0] + (float)l[0]) + xa.y * ((float)h[1] + (float)l[1])
               + xa.z * ((float)h[2] + (float)l[2]) + xa.w * ((float)h[3] + (float)l[3])
               + xb.x * ((float)h[4] + (float)l[4]) + xb.y * ((float)h[5] + (float)l[5])
               + xb.z * ((float)h[6] + (float)l[6]) + xb.w * ((float)h[7] + (float)l[7]);
        }
        LsT[tid][128] = (half_t)s;
    }
    __syncthreads();

    if (which == 1) {   // pooled phi -> pphi[m][d]
        const int m = tid >> 1, dh = (tid & 1) * 64;
        half8 o[8];
#pragma unroll
        for (int j = 0; j < 64; ++j) {
            float v0 = (float)LsT[dh + j][m];
            float v1 = (float)LsT[dh + j][m + 1];
            o[j >> 3][j & 7] = (half_t)fmaxf(v0, v1);
        }
        half8* dst = (half8*)&pphi[(size_t)(r0 + m) * D_ + dh];
#pragma unroll
        for (int j = 0; j < 8; ++j) dst[j] = o[j];
    } else {            // pooled g -> pgT[b][d][m]
        const int d = tid >> 1, mh = (tid & 1) * 64;
        const int b = r0 / N_, m0 = r0 & (N_ - 1);
        half8 in[8];
#pragma unroll
        for (int j = 0; j < 8; ++j) in[j] = *(const half8*)&LsT[d][mh + j * 8];
        const half_t ext = LsT[d][mh + 64];
        half8 o[8];
#pragma unroll
        for (int j = 0; j < 64; ++j) {
            float v0 = (float)in[j >> 3][j & 7];
            float v1 = (j == 63) ? (float)ext : (float)in[(j + 1) >> 3][(j + 1) & 7];
            o[j >> 3][j & 7] = (half_t)fmaxf(v0, v1);
        }
        half8* dst = (half8*)&pgT[((size_t)b * D_ + d) * N_ + m0 + mh];
#pragma unroll
        for (int j = 0; j < 8; ++j) dst[j] = o[j];
    }
}

// ---------------- MFMA flash attention, transposed scores, base-2 ----------
// KSPLIT=6 -> grid (32,6,4)=768 blocks = 3 blocks/CU (12 waves/CU).
// l kept as per-quad partials in the k-loop; cross-quad reduced in epilogue.
// block 256. LDS = 54,272 B (x3 = 162,816 <= 160 KiB).
__global__ __launch_bounds__(256, 3) void attn_kernel(
    const half_t* __restrict__ theta, const half_t* __restrict__ pphi,
    const half_t* __restrict__ pgT, half_t* __restrict__ ypart,
    float* __restrict__ mstat, float* __restrict__ lstat)
{
    const int tid = threadIdx.x;
    const int lane = tid & 63;
    const int w = tid >> 6;
    const int lm = lane & 15;
    const int lq = lane >> 4;      // 0..3
    const int qt = blockIdx.x, ksb = blockIdx.y, b = blockIdx.z;
    const int q0 = qt * 128;
    const int kt0 = (64 * ksb) / KSPLIT;       // uneven split: 10/11/11/10/11/11
    const int kt1 = (64 * (ksb + 1)) / KSPLIT;

    __shared__ half_t Ks[64][136];   // K tile [key][d]        17,408 B
    __shared__ half_t Gts[128][72];  // G tile [d][key]        18,432 B
    __shared__ half_t Ps[128][72];   // P [q][key] wave-private 18,432 B

    // Q B-frags (B[k=d][n=q]): direct fp16 loads (theta already *log2e)
    half8 qh[2][4];
#pragma unroll
    for (int nb = 0; nb < 2; ++nb) {
        const half_t* tr_ = theta + ((size_t)b * N_ + q0 + w * 32 + nb * 16 + lm) * D_;
#pragma unroll
        for (int k4 = 0; k4 < 4; ++k4)
            qh[nb][k4] = *(const half8*)(tr_ + k4 * 32 + lq * 8);
    }

    float m_i[2] = {-1e30f, -1e30f};
    float l_i[2] = {0.f, 0.f};      // per-quad partial (this lane's 16 keys/tile)
    f32x4 yacc[2][8];
#pragma unroll
    for (int mb = 0; mb < 2; ++mb)
#pragma unroll
        for (int dn = 0; dn < 8; ++dn)
#pragma unroll
            for (int r = 0; r < 4; ++r) yacc[mb][dn][r] = 0.f;

    for (int kt = kt0; kt < kt1; ++kt) {
        const int k0 = kt * 64;
        __syncthreads();
        {   // stage K [key][d] and G^T [d][key] cooperatively (coalesced)
            const int key = tid >> 2, ch = (tid & 3);
            const float4* src = (const float4*)(pphi +
                ((size_t)b * N_ + k0 + key) * D_ + ch * 32);
            float4 a0 = src[0], a1 = src[1], a2 = src[2], a3 = src[3];
            float4* dst = (float4*)&Ks[key][ch * 32];
            dst[0] = a0; dst[1] = a1; dst[2] = a2; dst[3] = a3;
            const int d = tid >> 1, kh = (tid & 1);
            const float4* gs = (const float4*)(pgT +
                ((size_t)b * D_ + d) * N_ + k0 + kh * 32);
            float4 g0 = gs[0], g1 = gs[1], g2 = gs[2], g3 = gs[3];
            float4* gd = (float4*)&Gts[d][kh * 32];
            gd[0] = g0; gd[1] = g1; gd[2] = g2; gd[3] = g3;
        }
        __syncthreads();

        // QK^T transposed: S^T[key][q]; A = K (LDS), B = Q (regs)
        f32x4 sc[4][2];
#pragma unroll
        for (int kb = 0; kb < 4; ++kb)
#pragma unroll
            for (int nb = 0; nb < 2; ++nb)
#pragma unroll
                for (int r = 0; r < 4; ++r) sc[kb][nb][r] = 0.f;
#pragma unroll
        for (int kb = 0; kb < 4; ++kb) {
#pragma unroll
            for (int k4 = 0; k4 < 4; ++k4) {
                half8 kf = *(const half8*)&Ks[kb * 16 + lm][k4 * 32 + lq * 8];
#pragma unroll
                for (int nb = 0; nb < 2; ++nb)
                    sc[kb][nb] = MFMA16x16x32(kf, qh[nb][k4], sc[kb][nb]);
            }
        }
        // mask padded key 4095 (only last tile of last split)
        if (k0 + 64 > M_) {
#pragma unroll
            for (int kb = 0; kb < 4; ++kb)
#pragma unroll
                for (int r = 0; r < 4; ++r)
                    if (k0 + kb * 16 + lq * 4 + r >= M_) {
                        sc[kb][0][r] = -1e30f; sc[kb][1][r] = -1e30f;
                    }
        }
        // online softmax (base-2): in-lane over 16 keys + 2 cross-quad max
        // shuffles (common m); l stays per-quad partial (no sum shuffles).
        float alpha[2];
#pragma unroll
        for (int nb = 0; nb < 2; ++nb) {
            float mt = -1e30f;
#pragma unroll
            for (int kb = 0; kb < 4; ++kb)
#pragma unroll
                for (int r = 0; r < 4; ++r) mt = fmaxf(mt, sc[kb][nb][r]);
            mt = fmaxf(mt, __shfl_xor(mt, 16, 64));
            mt = fmaxf(mt, __shfl_xor(mt, 32, 64));
            const float mnew = fmaxf(m_i[nb], mt);
            alpha[nb] = exp2f(m_i[nb] - mnew);
            m_i[nb] = mnew;
            float rs = 0.f;
#pragma unroll
            for (int kb = 0; kb < 4; ++kb)
#pragma unroll
                for (int r = 0; r < 4; ++r) {
                    float p = exp2f(sc[kb][nb][r] - mnew);
                    sc[kb][nb][r] = p;
                    rs += p;
                }
            l_i[nb] = l_i[nb] * alpha[nb] + rs;
            // P store: 4 consecutive keys at fixed q -> one b64 per (kb)
#pragma unroll
            for (int kb = 0; kb < 4; ++kb) {
                half4 pk;
#pragma unroll
                for (int r = 0; r < 4; ++r) pk[r] = (half_t)sc[kb][nb][r];
                *(half4*)&Ps[w * 32 + nb * 16 + lm][kb * 16 + lq * 4] = pk;
            }
        }
        // transpose alpha from (q=lm) lane layout to accumulator's (q=lq*4+r)
        float alpha_t[2][4];
#pragma unroll
        for (int mb = 0; mb < 2; ++mb)
#pragma unroll
            for (int r = 0; r < 4; ++r)
                alpha_t[mb][r] = __shfl(alpha[mb], lq * 4 + r, 16);
        // rescale accumulator
#pragma unroll
        for (int mb = 0; mb < 2; ++mb)
#pragma unroll
            for (int dn = 0; dn < 8; ++dn)
#pragma unroll
                for (int r = 0; r < 4; ++r) yacc[mb][dn][r] *= alpha_t[mb][r];
        // PV: A = P (LDS, wave-private -> no barrier), B = G^T (LDS)
        half8 pf[2][2];
#pragma unroll
        for (int mb = 0; mb < 2; ++mb)
#pragma unroll
            for (int k2 = 0; k2 < 2; ++k2)
                pf[mb][k2] = *(const half8*)&Ps[w * 32 + mb * 16 + lm][k2 * 32 + lq * 8];
#pragma unroll
        for (int dn = 0; dn < 8; ++dn) {
#pragma unroll
            for (int k2 = 0; k2 < 2; ++k2) {
                half8 gf = *(const half8*)&Gts[dn * 16 + lm][k2 * 32 + lq * 8];
                yacc[0][dn] = MFMA16x16x32(pf[0][k2], gf, yacc[0][dn]);
                yacc[1][dn] = MFMA16x16x32(pf[1][k2], gf, yacc[1][dn]);
            }
        }
    }

    // epilogue: finish l (cross-quad sum, deferred from the k-loop)
#pragma unroll
    for (int nb = 0; nb < 2; ++nb) {
        l_i[nb] += __shfl_xor(l_i[nb], 16, 64);
        l_i[nb] += __shfl_xor(l_i[nb], 32, 64);
    }
    // unnormalized y partial (fp16) + (m,l) stats (m in base-2)
    half_t* yp = ypart + ((size_t)ksb * BN_ + (size_t)b * N_) * D_;
#pragma unroll
    for (int mb = 0; mb < 2; ++mb)
#pragma unroll
        for (int dn = 0; dn < 8; ++dn)
#pragma unroll
            for (int r = 0; r < 4; ++r)
                yp[(size_t)(q0 + w * 32 + mb * 16 + lq * 4 + r) * D_ + dn * 16 + lm] =
                    (half_t)yacc[mb][dn][r];
    if (lq == 0) {
#pragma unroll
        for (int nb = 0; nb < 2; ++nb) {
            const int row = q0 + w * 32 + nb * 16 + lm;
            mstat[(size_t)ksb * BN_ + (size_t)b * N_ + row] = m_i[nb];
            lstat[(size_t)ksb * BN_ + (size_t)b * N_ + row] = l_i[nb];
        }
    }
}

// ---- final (MFMA): merge 6 partials (base-2 stats), z = x + y @ Wf ----
// grid (BN_/128, 2), block 256. LDS = 39,936 B.
__global__ __launch_bounds__(256) void final_kernel(
    const half_t* __restrict__ ypart, const float* __restrict__ mstat,
    const float* __restrict__ lstat, const float* __restrict__ x,
    const half_t* __restrict__ WfT, float* __restrict__ out)
{
    const int tid = threadIdx.x;
    const int lane = tid & 63;
    const int w = tid >> 6;
    const int lm = lane & 15;
    const int lq = lane >> 4;
    const int r0 = blockIdx.x * 128;
    const int c0 = blockIdx.y * 128;

    __shared__ half_t Ys[128][72];
    __shared__ half_t Wfs[128][72];
    __shared__ float scl[KSPLIT][128];

    if (tid < 128) {
        const int row = r0 + tid;
        float mv[KSPLIT], lv[KSPLIT], wv[KSPLIT];
        float Mx = -1e30f;
#pragma unroll
        for (int s = 0; s < KSPLIT; ++s) {
            mv[s] = mstat[(size_t)s * BN_ + row];
            lv[s] = lstat[(size_t)s * BN_ + row];
            Mx = fmaxf(Mx, mv[s]);
        }
        float lsum = 0.f;
#pragma unroll
        for (int s = 0; s < KSPLIT; ++s) { wv[s] = exp2f(mv[s] - Mx); lsum += wv[s] * lv[s]; }
        const float inv = 1.f / lsum;
#pragma unroll
        for (int s = 0; s < KSPLIT; ++s) scl[s][tid] = wv[s] * inv;
    }
    __syncthreads();

    f32x4 acc[2][8];
#pragma unroll
    for (int rb = 0; rb < 2; ++rb)
#pragma unroll
        for (int nb = 0; nb < 8; ++nb)
#pragma unroll
            for (int r = 0; r < 4; ++r) acc[rb][nb][r] = 0.f;

    const int sr = tid >> 1;
    const int dd = (tid & 1) * 32;

    for (int kc = 0; kc < 2; ++kc) {
        {
            float ss[KSPLIT];
#pragma unroll
            for (int s = 0; s < KSPLIT; ++s) ss[s] = scl[s][sr];
            const size_t yb = (size_t)(r0 + sr) * D_ + kc * 64 + dd;
            half8 o[4];
#pragma unroll
            for (int q = 0; q < 4; ++q) {
                float m[8];
#pragma unroll
                for (int j = 0; j < 8; ++j) m[j] = 0.f;
#pragma unroll
                for (int s = 0; s < KSPLIT; ++s) {
                    half8 yv = *(const half8*)&ypart[(size_t)s * BN_ * D_ + yb + q * 8];
#pragma unroll
                    for (int j = 0; j < 8; ++j) m[j] += ss[s] * (float)yv[j];
                }
#pragma unroll
                for (int j = 0; j < 8; ++j) o[q][j] = (half_t)m[j];
            }
#pragma unroll
            for (int q = 0; q < 4; ++q) *(half8*)&Ys[sr][dd + q * 8] = o[q];
            const half_t* wf = WfT + (size_t)(c0 + sr) * D_ + kc * 64 + dd;
#pragma unroll
            for (int q = 0; q < 4; ++q)
                *(half8*)&Wfs[sr][dd + q * 8] = *(const half8*)&wf[q * 8];
        }
        __syncthreads();

        half8 af[2][2];
#pragma unroll
        for (int rb = 0; rb < 2; ++rb)
#pragma unroll
            for (int k2 = 0; k2 < 2; ++k2)
                af[rb][k2] = *(const half8*)&Ys[w * 32 + rb * 16 + lm][k2 * 32 + lq * 8];
#pragma unroll
        for (int nb = 0; nb < 8; ++nb) {
#pragma unroll
            for (int k2 = 0; k2 < 2; ++k2) {
                half8 bf = *(const half8*)&Wfs[nb * 16 + lm][k2 * 32 + lq * 8];
                acc[0][nb] = MFMA16x16x32(af[0][k2], bf, acc[0][nb]);
                acc[1][nb] = MFMA16x16x32(af[1][k2], bf, acc[1][nb]);
            }
        }
        __syncthreads();
    }
#pragma unroll
    for (int rb = 0; rb < 2; ++rb)
#pragma unroll
        for (int nb = 0; nb < 8; ++nb)
#pragma unroll
            for (int r = 0; r < 4; ++r) {
                const int row = r0 + w * 32 + rb * 16 + lq * 4 + r;
                const int col = c0 + nb * 16 + lm;
                out[(size_t)row * C_ + col] =
                    acc[rb][nb][r] + x[(size_t)row * C_ + col];
            }
}

extern "C" void kernel_launch(void* const* d_in, const int* in_sizes, int n_in,
                              void* d_out, int out_size, void* d_ws, size_t ws_size,
                              hipStream_t stream)
{
    const float* x  = (const float*)d_in[0];
    const float* Wt = (const float*)d_in[1];
    const float* Wp = (const float*)d_in[2];
    const float* Wg = (const float*)d_in[3];
    const float* Wf = (const float*)d_in[4];
    float* out = (float*)d_out;

    // ws (fp32 words, SEG = BN_*D_):
    //   theta f16 (SEG/2 w) | pphi f16 | pgT f16 | ypart f16 x6 (3 SEG w)
    //   | mstat | lstat | WT_hi/lo | WfT   -> total ~37.3 MB
    const size_t SEG = (size_t)BN_ * D_;   // 2,097,152
    float* ws     = (float*)d_ws;
    half_t* theta = (half_t*)ws;
    half_t* pphi  = (half_t*)(ws + SEG / 2);
    half_t* pgT   = (half_t*)(ws + SEG);
    half_t* ypart = (half_t*)(ws + SEG + SEG / 2);
    float* mstat  = ws + SEG + SEG / 2 + 3 * SEG;          // after 6 f16 segs
    float* lstat  = mstat + (size_t)KSPLIT * BN_;
    half_t* WT_hi = (half_t*)(lstat + (size_t)KSPLIT * BN_);
    half_t* WT_lo = WT_hi + 3 * 32768;
    half_t* WfT   = WT_lo + 3 * 32768;

    prep_kernel<<<dim3(128, 4), 256, 0, stream>>>(Wt, Wp, Wg, Wf, WT_hi, WT_lo, WfT);
    proj_kernel<<<dim3(BN_ / 128, 3), 256, 0, stream>>>(x, WT_hi, WT_lo,
                                                        theta, pphi, pgT);
    attn_kernel<<<dim3(N_ / 128, KSPLIT, B_), 256, 0, stream>>>(
        theta, pphi, pgT, ypart, mstat, lstat);
    final_kernel<<<dim3(BN_ / 128, 2), 256, 0, stream>>>(
        ypart, mstat, lstat, x, WfT, out);
}

// Round 11
// 176.135 us; speedup vs baseline: 1.1874x; 1.1874x over previous
//
#include <hip/hip_runtime.h>

#define B_  4
#define N_  4096
#define C_  256
#define D_  128
#define M_  4095
#define BN_ (B_ * N_)
#define KSPLIT 4

typedef _Float16 half_t;
typedef __attribute__((ext_vector_type(8))) _Float16 half8;
typedef __attribute__((ext_vector_type(4))) _Float16 half4;
typedef __attribute__((ext_vector_type(4))) float f32x4;

#define MFMA16x16x32(A, B, C) __builtin_amdgcn_mfma_f32_16x16x32_f16(A, B, C, 0, 0, 0)
#define LOG2E 1.44269504088896f

// ---- prep: weights into B-fragment layouts (runs once, tiny) ----
// wsel 0..2: WT_hi[which][d][c] fp16 from {Wt,Wp,Wg}[c][d]; wsel 3: WfT[c][d].
__global__ __launch_bounds__(256) void prep_kernel(
    const float* __restrict__ Wt, const float* __restrict__ Wp,
    const float* __restrict__ Wg, const float* __restrict__ Wf,
    half_t* __restrict__ WT_hi, half_t* __restrict__ WfT)
{
    const int idx = blockIdx.x * 256 + threadIdx.x;   // 0..32767
    const int wsel = blockIdx.y;
    if (wsel < 3) {
        const float* __restrict__ W = (wsel == 0) ? Wt : (wsel == 1) ? Wp : Wg;
        const int d = idx >> 8, c = idx & 255;
        WT_hi[(size_t)wsel * 32768 + idx] = (half_t)W[(size_t)c * D_ + d];
    } else {
        const int c = idx >> 7, d = idx & 127;
        WfT[idx] = (half_t)Wf[(size_t)d * C_ + c];
    }
}

// ---- proj (single-fp16 MFMA) + FUSED maxpool/transpose ----
// which: 0 = theta*log2e -> f16 [n][d]; 1 = phi -> pphi[m][d] f16;
// 2 = g -> pgT[b][d][m] f16. grid (BN_/64, 3) = 768 blocks (3/CU), block 256.
// LDS = 18,432 B (GEMM staging 15,360 overlaid by pool buffer 18,432).
__global__ __launch_bounds__(256) void proj_kernel(
    const float* __restrict__ x, const half_t* __restrict__ WT_hi,
    half_t* __restrict__ theta, half_t* __restrict__ pphi,
    half_t* __restrict__ pgT)
{
    const int tid = threadIdx.x;
    const int lane = tid & 63;
    const int w = tid >> 6;        // wave -> rows w*16 .. w*16+15
    const int lm = lane & 15;
    const int lq = lane >> 4;
    const int r0 = blockIdx.x * 64;
    const int which = blockIdx.y;
    const half_t* __restrict__ Wg_ = WT_hi + (size_t)which * 32768;

    __shared__ __align__(16) unsigned char lds_raw[18432];
    half_t (*Xh)[40]  = (half_t (*)[40])(lds_raw);            //  64 x 40 =  5,120 B
    half_t (*Whl)[40] = (half_t (*)[40])(lds_raw + 5120);     // 128 x 40 = 10,240 B

    f32x4 acc[8];
#pragma unroll
    for (int nb = 0; nb < 8; ++nb)
#pragma unroll
        for (int r = 0; r < 4; ++r) acc[nb][r] = 0.f;

    const int xr = tid >> 2, xc = (tid & 3) * 8;   // x stage: 64r x 32c
    const int wr = tid >> 1, wc = (tid & 1) * 16;  // W stage: 128d x 32c

    for (int kc = 0; kc < 8; ++kc) {   // C = 256 in chunks of 32
        __syncthreads();
        {
            const float* xs = x + (size_t)(r0 + xr) * C_ + kc * 32 + xc;
            float4 v0 = *(const float4*)&xs[0], v1 = *(const float4*)&xs[4];
            half8 hi;
            hi[0] = (half_t)v0.x; hi[1] = (half_t)v0.y;
            hi[2] = (half_t)v0.z; hi[3] = (half_t)v0.w;
            hi[4] = (half_t)v1.x; hi[5] = (half_t)v1.y;
            hi[6] = (half_t)v1.z; hi[7] = (half_t)v1.w;
            *(half8*)&Xh[xr][xc] = hi;
            const half_t* wsrc = Wg_ + (size_t)wr * 256 + kc * 32 + wc;
            *(half8*)&Whl[wr][wc]     = *(const half8*)&wsrc[0];
            *(half8*)&Whl[wr][wc + 8] = *(const half8*)&wsrc[8];
        }
        __syncthreads();

        half8 ah = *(const half8*)&Xh[w * 16 + lm][lq * 8];
#pragma unroll
        for (int nb = 0; nb < 8; ++nb) {
            half8 bh = *(const half8*)&Whl[nb * 16 + lm][lq * 8];
            acc[nb] = MFMA16x16x32(ah, bh, acc[nb]);
        }
    }

    if (which == 0) {   // theta: scale by log2e, store fp16 (QK runs in base-2)
#pragma unroll
        for (int nb = 0; nb < 8; ++nb)
#pragma unroll
            for (int r = 0; r < 4; ++r)
                theta[(size_t)(r0 + w * 16 + lq * 4 + r) * D_ + nb * 16 + lm] =
                    (half_t)(acc[nb][r] * LOG2E);
        return;
    }

    // ---- fused pool path: acc -> LsT[d][m] fp16, halo row, pool, store ----
    __syncthreads();   // staging arrays dead
    half_t (*LsT)[72] = (half_t (*)[72])(lds_raw);   // 128 x 72 = 18,432 B
#pragma unroll
    for (int nb = 0; nb < 8; ++nb) {
        const int d = nb * 16 + lm;
        const int m = w * 16 + lq * 4;
        half4 pk;
#pragma unroll
        for (int r = 0; r < 4; ++r) pk[r] = (half_t)acc[nb][r];
        *(half4*)&LsT[d][m] = pk;
    }
    // halo: projected row r0+64 (or r0+63 at batch boundary) -> LsT[d][64]
    if (tid < 128) {
        int rh = r0 + 64;
        if ((rh & (N_ - 1)) == 0) rh = r0 + 63;
        const float* xrow = x + (size_t)rh * C_;
        const half_t* wrow = Wg_ + (size_t)tid * 256;
        float s = 0.f;
#pragma unroll
        for (int c8 = 0; c8 < 32; ++c8) {
            half8 h = *(const half8*)&wrow[c8 * 8];
            float4 xa = *(const float4*)&xrow[c8 * 8];
            float4 xb = *(const float4*)&xrow[c8 * 8 + 4];
            s += xa.x * (float)h[0] + xa.y * (float)h[1]
               + xa.z * (float)h[2] + xa.w * (float)h[3]
               + xb.x * (float)h[4] + xb.y * (float)h[5]
               + xb.z * (float)h[6] + xb.w * (float)h[7];
        }
        LsT[tid][64] = (half_t)s;
    }
    __syncthreads();

    if (which == 1) {   // pooled phi -> pphi[m][d]
        const int m = tid >> 2, dh = (tid & 3) * 32;
        half8 o[4];
#pragma unroll
        for (int j = 0; j < 32; ++j) {
            float v0 = (float)LsT[dh + j][m];
            float v1 = (float)LsT[dh + j][m + 1];
            o[j >> 3][j & 7] = (half_t)fmaxf(v0, v1);
        }
        half8* dst = (half8*)&pphi[(size_t)(r0 + m) * D_ + dh];
#pragma unroll
        for (int j = 0; j < 4; ++j) dst[j] = o[j];
    } else {            // pooled g -> pgT[b][d][m]
        const int d = tid >> 1, mh = (tid & 1) * 32;
        const int b = r0 / N_, m0 = r0 & (N_ - 1);
        half8 in[4];
#pragma unroll
        for (int j = 0; j < 4; ++j) in[j] = *(const half8*)&LsT[d][mh + j * 8];
        const half_t ext = LsT[d][mh + 32];
        half8 o[4];
#pragma unroll
        for (int j = 0; j < 32; ++j) {
            float v0 = (float)in[j >> 3][j & 7];
            float v1 = (j == 31) ? (float)ext : (float)in[(j + 1) >> 3][(j + 1) & 7];
            o[j >> 3][j & 7] = (half_t)fmaxf(v0, v1);
        }
        half8* dst = (half8*)&pgT[((size_t)b * D_ + d) * N_ + m0 + mh];
#pragma unroll
        for (int j = 0; j < 4; ++j) dst[j] = o[j];
    }
}

// ---------------- MFMA flash attention, transposed scores, base-2 ----------
// r9 configuration (KSPLIT=4, 2 blocks/CU) + deferred-l epilogue reduction.
// grid (N_/128, KSPLIT, B_) = 512 blocks, 256 thr. LDS = 54,272 B.
__global__ __launch_bounds__(256, 2) void attn_kernel(
    const half_t* __restrict__ theta, const half_t* __restrict__ pphi,
    const half_t* __restrict__ pgT, half_t* __restrict__ ypart,
    float* __restrict__ mstat, float* __restrict__ lstat)
{
    const int tid = threadIdx.x;
    const int lane = tid & 63;
    const int w = tid >> 6;
    const int lm = lane & 15;
    const int lq = lane >> 4;      // 0..3
    const int qt = blockIdx.x, ksb = blockIdx.y, b = blockIdx.z;
    const int q0 = qt * 128;
    const int kt0 = ksb * 16, kt1 = kt0 + 16;

    __shared__ half_t Ks[64][136];   // K tile [key][d]        17,408 B
    __shared__ half_t Gts[128][72];  // G tile [d][key]        18,432 B
    __shared__ half_t Ps[128][72];   // P [q][key] wave-private 18,432 B

    // Q B-frags (B[k=d][n=q]): direct fp16 loads (theta already *log2e)
    half8 qh[2][4];
#pragma unroll
    for (int nb = 0; nb < 2; ++nb) {
        const half_t* tr_ = theta + ((size_t)b * N_ + q0 + w * 32 + nb * 16 + lm) * D_;
#pragma unroll
        for (int k4 = 0; k4 < 4; ++k4)
            qh[nb][k4] = *(const half8*)(tr_ + k4 * 32 + lq * 8);
    }

    float m_i[2] = {-1e30f, -1e30f};
    float l_i[2] = {0.f, 0.f};      // per-quad partial; cross-quad sum deferred
    f32x4 yacc[2][8];
#pragma unroll
    for (int mb = 0; mb < 2; ++mb)
#pragma unroll
        for (int dn = 0; dn < 8; ++dn)
#pragma unroll
            for (int r = 0; r < 4; ++r) yacc[mb][dn][r] = 0.f;

    for (int kt = kt0; kt < kt1; ++kt) {
        const int k0 = kt * 64;
        __syncthreads();
        {   // stage K [key][d] and G^T [d][key] cooperatively (coalesced)
            const int key = tid >> 2, ch = (tid & 3);
            const float4* src = (const float4*)(pphi +
                ((size_t)b * N_ + k0 + key) * D_ + ch * 32);
            float4 a0 = src[0], a1 = src[1], a2 = src[2], a3 = src[3];
            float4* dst = (float4*)&Ks[key][ch * 32];
            dst[0] = a0; dst[1] = a1; dst[2] = a2; dst[3] = a3;
            const int d = tid >> 1, kh = (tid & 1);
            const float4* gs = (const float4*)(pgT +
                ((size_t)b * D_ + d) * N_ + k0 + kh * 32);
            float4 g0 = gs[0], g1 = gs[1], g2 = gs[2], g3 = gs[3];
            float4* gd = (float4*)&Gts[d][kh * 32];
            gd[0] = g0; gd[1] = g1; gd[2] = g2; gd[3] = g3;
        }
        __syncthreads();

        // QK^T transposed: S^T[key][q]; A = K (LDS), B = Q (regs)
        f32x4 sc[4][2];
#pragma unroll
        for (int kb = 0; kb < 4; ++kb)
#pragma unroll
            for (int nb = 0; nb < 2; ++nb)
#pragma unroll
                for (int r = 0; r < 4; ++r) sc[kb][nb][r] = 0.f;
#pragma unroll
        for (int kb = 0; kb < 4; ++kb) {
#pragma unroll
            for (int k4 = 0; k4 < 4; ++k4) {
                half8 kf = *(const half8*)&Ks[kb * 16 + lm][k4 * 32 + lq * 8];
#pragma unroll
                for (int nb = 0; nb < 2; ++nb)
                    sc[kb][nb] = MFMA16x16x32(kf, qh[nb][k4], sc[kb][nb]);
            }
        }
        // mask padded key 4095 (only last tile of last split)
        if (k0 + 64 > M_) {
#pragma unroll
            for (int kb = 0; kb < 4; ++kb)
#pragma unroll
                for (int r = 0; r < 4; ++r)
                    if (k0 + kb * 16 + lq * 4 + r >= M_) {
                        sc[kb][0][r] = -1e30f; sc[kb][1][r] = -1e30f;
                    }
        }
        // online softmax (base-2): in-lane over 16 keys + 2 cross-quad max
        // shuffles (common m); l stays per-quad partial.
        float alpha[2];
#pragma unroll
        for (int nb = 0; nb < 2; ++nb) {
            float mt = -1e30f;
#pragma unroll
            for (int kb = 0; kb < 4; ++kb)
#pragma unroll
                for (int r = 0; r < 4; ++r) mt = fmaxf(mt, sc[kb][nb][r]);
            mt = fmaxf(mt, __shfl_xor(mt, 16, 64));
            mt = fmaxf(mt, __shfl_xor(mt, 32, 64));
            const float mnew = fmaxf(m_i[nb], mt);
            alpha[nb] = exp2f(m_i[nb] - mnew);
            m_i[nb] = mnew;
            float rs = 0.f;
#pragma unroll
            for (int kb = 0; kb < 4; ++kb)
#pragma unroll
                for (int r = 0; r < 4; ++r) {
                    float p = exp2f(sc[kb][nb][r] - mnew);
                    sc[kb][nb][r] = p;
                    rs += p;
                }
            l_i[nb] = l_i[nb] * alpha[nb] + rs;
            // P store: 4 consecutive keys at fixed q -> one b64 per (kb)
#pragma unroll
            for (int kb = 0; kb < 4; ++kb) {
                half4 pk;
#pragma unroll
                for (int r = 0; r < 4; ++r) pk[r] = (half_t)sc[kb][nb][r];
                *(half4*)&Ps[w * 32 + nb * 16 + lm][kb * 16 + lq * 4] = pk;
            }
        }
        // transpose alpha from (q=lm) lane layout to accumulator's (q=lq*4+r)
        float alpha_t[2][4];
#pragma unroll
        for (int mb = 0; mb < 2; ++mb)
#pragma unroll
            for (int r = 0; r < 4; ++r)
                alpha_t[mb][r] = __shfl(alpha[mb], lq * 4 + r, 16);
        // rescale accumulator
#pragma unroll
        for (int mb = 0; mb < 2; ++mb)
#pragma unroll
            for (int dn = 0; dn < 8; ++dn)
#pragma unroll
                for (int r = 0; r < 4; ++r) yacc[mb][dn][r] *= alpha_t[mb][r];
        // PV: A = P (LDS, wave-private -> no barrier), B = G^T (LDS)
        half8 pf[2][2];
#pragma unroll
        for (int mb = 0; mb < 2; ++mb)
#pragma unroll
            for (int k2 = 0; k2 < 2; ++k2)
                pf[mb][k2] = *(const half8*)&Ps[w * 32 + mb * 16 + lm][k2 * 32 + lq * 8];
#pragma unroll
        for (int dn = 0; dn < 8; ++dn) {
#pragma unroll
            for (int k2 = 0; k2 < 2; ++k2) {
                half8 gf = *(const half8*)&Gts[dn * 16 + lm][k2 * 32 + lq * 8];
                yacc[0][dn] = MFMA16x16x32(pf[0][k2], gf, yacc[0][dn]);
                yacc[1][dn] = MFMA16x16x32(pf[1][k2], gf, yacc[1][dn]);
            }
        }
    }

    // epilogue: finish l (cross-quad sum, deferred from the k-loop)
#pragma unroll
    for (int nb = 0; nb < 2; ++nb) {
        l_i[nb] += __shfl_xor(l_i[nb], 16, 64);
        l_i[nb] += __shfl_xor(l_i[nb], 32, 64);
    }
    // unnormalized y partial (fp16) + (m,l) stats (m in base-2)
    half_t* yp = ypart + ((size_t)ksb * BN_ + (size_t)b * N_) * D_;
#pragma unroll
    for (int mb = 0; mb < 2; ++mb)
#pragma unroll
        for (int dn = 0; dn < 8; ++dn)
#pragma unroll
            for (int r = 0; r < 4; ++r)
                yp[(size_t)(q0 + w * 32 + mb * 16 + lq * 4 + r) * D_ + dn * 16 + lm] =
                    (half_t)yacc[mb][dn][r];
    if (lq == 0) {
#pragma unroll
        for (int nb = 0; nb < 2; ++nb) {
            const int row = q0 + w * 32 + nb * 16 + lm;
            mstat[(size_t)ksb * BN_ + (size_t)b * N_ + row] = m_i[nb];
            lstat[(size_t)ksb * BN_ + (size_t)b * N_ + row] = l_i[nb];
        }
    }
}

// ---- final (MFMA): merge 4 partials (base-2 stats), z = x + y @ Wf ----
// grid (BN_/128, 2), block 256. LDS = 38,912 B.
__global__ __launch_bounds__(256) void final_kernel(
    const half_t* __restrict__ ypart, const float* __restrict__ mstat,
    const float* __restrict__ lstat, const float* __restrict__ x,
    const half_t* __restrict__ WfT, float* __restrict__ out)
{
    const int tid = threadIdx.x;
    const int lane = tid & 63;
    const int w = tid >> 6;
    const int lm = lane & 15;
    const int lq = lane >> 4;
    const int r0 = blockIdx.x * 128;
    const int c0 = blockIdx.y * 128;

    __shared__ half_t Ys[128][72];
    __shared__ half_t Wfs[128][72];
    __shared__ float scl[KSPLIT][128];

    if (tid < 128) {
        const int row = r0 + tid;
        float mv[KSPLIT], lv[KSPLIT], wv[KSPLIT];
        float Mx = -1e30f;
#pragma unroll
        for (int s = 0; s < KSPLIT; ++s) {
            mv[s] = mstat[(size_t)s * BN_ + row];
            lv[s] = lstat[(size_t)s * BN_ + row];
            Mx = fmaxf(Mx, mv[s]);
        }
        float lsum = 0.f;
#pragma unroll
        for (int s = 0; s < KSPLIT; ++s) { wv[s] = exp2f(mv[s] - Mx); lsum += wv[s] * lv[s]; }
        const float inv = 1.f / lsum;
#pragma unroll
        for (int s = 0; s < KSPLIT; ++s) scl[s][tid] = wv[s] * inv;
    }
    __syncthreads();

    f32x4 acc[2][8];
#pragma unroll
    for (int rb = 0; rb < 2; ++rb)
#pragma unroll
        for (int nb = 0; nb < 8; ++nb)
#pragma unroll
            for (int r = 0; r < 4; ++r) acc[rb][nb][r] = 0.f;

    const int sr = tid >> 1;
    const int dd = (tid & 1) * 32;

    for (int kc = 0; kc < 2; ++kc) {
        {
            float ss[KSPLIT];
#pragma unroll
            for (int s = 0; s < KSPLIT; ++s) ss[s] = scl[s][sr];
            const size_t yb = (size_t)(r0 + sr) * D_ + kc * 64 + dd;
            half8 o[4];
#pragma unroll
            for (int q = 0; q < 4; ++q) {
                float m[8];
#pragma unroll
                for (int j = 0; j < 8; ++j) m[j] = 0.f;
#pragma unroll
                for (int s = 0; s < KSPLIT; ++s) {
                    half8 yv = *(const half8*)&ypart[(size_t)s * BN_ * D_ + yb + q * 8];
#pragma unroll
                    for (int j = 0; j < 8; ++j) m[j] += ss[s] * (float)yv[j];
                }
#pragma unroll
                for (int j = 0; j < 8; ++j) o[q][j] = (half_t)m[j];
            }
#pragma unroll
            for (int q = 0; q < 4; ++q) *(half8*)&Ys[sr][dd + q * 8] = o[q];
            const half_t* wf = WfT + (size_t)(c0 + sr) * D_ + kc * 64 + dd;
#pragma unroll
            for (int q = 0; q < 4; ++q)
                *(half8*)&Wfs[sr][dd + q * 8] = *(const half8*)&wf[q * 8];
        }
        __syncthreads();

        half8 af[2][2];
#pragma unroll
        for (int rb = 0; rb < 2; ++rb)
#pragma unroll
            for (int k2 = 0; k2 < 2; ++k2)
                af[rb][k2] = *(const half8*)&Ys[w * 32 + rb * 16 + lm][k2 * 32 + lq * 8];
#pragma unroll
        for (int nb = 0; nb < 8; ++nb) {
#pragma unroll
            for (int k2 = 0; k2 < 2; ++k2) {
                half8 bf = *(const half8*)&Wfs[nb * 16 + lm][k2 * 32 + lq * 8];
                acc[0][nb] = MFMA16x16x32(af[0][k2], bf, acc[0][nb]);
                acc[1][nb] = MFMA16x16x32(af[1][k2], bf, acc[1][nb]);
            }
        }
        __syncthreads();
    }
#pragma unroll
    for (int rb = 0; rb < 2; ++rb)
#pragma unroll
        for (int nb = 0; nb < 8; ++nb)
#pragma unroll
            for (int r = 0; r < 4; ++r) {
                const int row = r0 + w * 32 + rb * 16 + lq * 4 + r;
                const int col = c0 + nb * 16 + lm;
                out[(size_t)row * C_ + col] =
                    acc[rb][nb][r] + x[(size_t)row * C_ + col];
            }
}

extern "C" void kernel_launch(void* const* d_in, const int* in_sizes, int n_in,
                              void* d_out, int out_size, void* d_ws, size_t ws_size,
                              hipStream_t stream)
{
    const float* x  = (const float*)d_in[0];
    const float* Wt = (const float*)d_in[1];
    const float* Wp = (const float*)d_in[2];
    const float* Wg = (const float*)d_in[3];
    const float* Wf = (const float*)d_in[4];
    float* out = (float*)d_out;

    // ws (fp32 words, SEG = BN_*D_):
    //   theta f16 [0,0.5) | pphi f16 [0.5,1) | pgT f16 [1,1.5)
    //   ypart f16 x4 [1.5,3.5) | mstat | lstat | WT_hi | WfT  (~30 MB)
    const size_t SEG = (size_t)BN_ * D_;   // 2,097,152
    float* ws     = (float*)d_ws;
    half_t* theta = (half_t*)ws;
    half_t* pphi  = (half_t*)(ws + SEG / 2);
    half_t* pgT   = (half_t*)(ws + SEG);
    half_t* ypart = (half_t*)(ws + SEG + SEG / 2);
    float* mstat  = ws + 3 * SEG + SEG / 2;
    float* lstat  = mstat + (size_t)KSPLIT * BN_;
    half_t* WT_hi = (half_t*)(lstat + (size_t)KSPLIT * BN_);
    half_t* WfT   = WT_hi + 3 * 32768;

    prep_kernel<<<dim3(128, 4), 256, 0, stream>>>(Wt, Wp, Wg, Wf, WT_hi, WfT);
    proj_kernel<<<dim3(BN_ / 64, 3), 256, 0, stream>>>(x, WT_hi, theta, pphi, pgT);
    attn_kernel<<<dim3(N_ / 128, KSPLIT, B_), 256, 0, stream>>>(
        theta, pphi, pgT, ypart, mstat, lstat);
    final_kernel<<<dim3(BN_ / 128, 2), 256, 0, stream>>>(
        ypart, mstat, lstat, x, WfT, out);
}